// Round 13
// baseline (68.422 us; speedup 1.0000x reference)
//
#include <hip/hip_runtime.h>

// NCC loss (B=2, C=1, 160^3 f32, 9^3 box window). Two passes + reduce.
// pass_zx: products + 4-wide sliding z-window in regs; subtract-slices come
//          from a 5-slice register save-list (init window) instead of global
//          re-loads -> 14 taps/chunk instead of 19. x-window via f32 LDS row
//          staging (2 barriers/dz, proven). -> fp8 bufA [b][z][y][f][x].
// pass_y : thin y-slide (8-wide, CHY=2) over xz-windowed fp8 rows + cc +
//          deterministic reduction (proven).
// finalize: deterministic reduce.

typedef float floatx2 __attribute__((ext_vector_type(2)));

constexpr int W = 160, H = 160, D = 160;
constexpr int SLICE = W * H;
constexpr int NVOX  = W * H * D;
constexpr int BATCH = 2;
constexpr int FROW  = 5 * W;             // 800 B per (b,z,y) row-group
constexpr float RW  = 1.0f / 729.0f;

// pass_zx geometry
constexpr int TPB_ZX = 320;              // 8 rows x 40 x-groups
constexpr int ROWS_PB = 8;
constexpr int XGZ   = W / 4;             // 40
constexpr int CHZ   = 5, NCHZ = D / CHZ; // 32 z-chunks (sub-slices == init slices)
constexpr int NTUP_ZX = BATCH * NCHZ * H;        // 10,240 (b,c,y) rows
constexpr int NBLK_ZX = NTUP_ZX / ROWS_PB;       // 1280
constexpr int LROW  = 168;               // 4 zero-pad | 160 | 4 zero-pad (f32)

// pass_y geometry (proven thin config)
constexpr int TPB_Y = 256;
constexpr int XGY   = W / 8;             // 20
constexpr int CHY   = 2, NCHY = H / CHY; // 80
constexpr int NTH_Y = BATCH * D * NCHY * XGY;    // 512,000
constexpr int NBLK_Y = NTH_Y / TPB_Y;            // 2000

// ---- fp8 helpers (HW cvt, OCP e4m3) --------------------------------------
__device__ inline unsigned int pk4(float a, float b, float c, float d) {
    unsigned int u = 0;
    u = __builtin_amdgcn_cvt_pk_fp8_f32(a, b, u, false);
    u = __builtin_amdgcn_cvt_pk_fp8_f32(c, d, u, true);
    return u;
}
__device__ inline void up8(uint2 v, float* o) {
    floatx2 t;
    t = __builtin_amdgcn_cvt_pk_f32_fp8(v.x, false); o[0] = t[0]; o[1] = t[1];
    t = __builtin_amdgcn_cvt_pk_f32_fp8(v.x, true);  o[2] = t[0]; o[3] = t[1];
    t = __builtin_amdgcn_cvt_pk_f32_fp8(v.y, false); o[4] = t[0]; o[5] = t[1];
    t = __builtin_amdgcn_cvt_pk_f32_fp8(v.y, true);  o[6] = t[0]; o[7] = t[1];
}

// ---- pass 1: z-window (regs, save-list subs) + x-window (LDS staging) ----
__global__ __launch_bounds__(TPB_ZX) void pass_zx(const float* __restrict__ I,
                                                  const float* __restrict__ J,
                                                  unsigned char* __restrict__ outA) {
    __shared__ float lds[ROWS_PB][5][LROW];

    int tid = threadIdx.x;
    int r  = tid / XGZ;                  // 0..7 row-in-block
    int xg = tid % XGZ;                  // 0..39
    int tuple = blockIdx.x * ROWS_PB + r;
    int y = tuple % H;
    int c = (tuple / H) % NCHZ;
    int b = tuple / (H * NCHZ);
    int x0 = xg * 4;
    const float* Ib = I + (size_t)b * NVOX + y * W + x0;
    const float* Jb = J + (size_t)b * NVOX + y * W + x0;
    unsigned char* ob = outA + ((size_t)b * D * H + y) * FROW + x0;

    // zero the halo pads once
    if (xg == 0) {
#pragma unroll
        for (int f = 0; f < 5; ++f) {
            lds[r][f][0] = 0.f; lds[r][f][1] = 0.f;
            lds[r][f][2] = 0.f; lds[r][f][3] = 0.f;
        }
    }
    if (xg == XGZ - 1) {
#pragma unroll
        for (int f = 0; f < 5; ++f) {
            lds[r][f][164] = 0.f; lds[r][f][165] = 0.f;
            lds[r][f][166] = 0.f; lds[r][f][167] = 0.f;
        }
    }

    float s[5][4];
#pragma unroll
    for (int f = 0; f < 5; ++f)
#pragma unroll
        for (int i = 0; i < 4; ++i) s[f][i] = 0.f;

    const float4 Z4 = make_float4(0.f, 0.f, 0.f, 0.f);
    int z0 = c * CHZ;

    // init window z0-4 .. z0+4; SAVE slices z0-4..z0 (the future subtracts)
    float4 savI[CHZ], savJ[CHZ];
#pragma unroll
    for (int k = 0; k < 9; ++k) {
        int zz = z0 - 4 + k;
        bool in = (zz >= 0);             // zz <= z0+4 <= 159 always
        float4 a = in ? *(const float4*)(Ib + (size_t)zz * SLICE) : Z4;
        float4 bb = in ? *(const float4*)(Jb + (size_t)zz * SLICE) : Z4;
        if (k < CHZ) { savI[k] = a; savJ[k] = bb; }
        float av[4] = {a.x, a.y, a.z, a.w};
        float bv[4] = {bb.x, bb.y, bb.z, bb.w};
#pragma unroll
        for (int i = 0; i < 4; ++i) {
            float x = av[i], yv = bv[i];
            s[0][i] += x; s[1][i] += yv;
            s[2][i] += x * x; s[3][i] += yv * yv; s[4][i] += x * yv;
        }
    }

#pragma unroll
    for (int dz = 0; dz < CHZ; ++dz) {
        int z = z0 + dz;
        int za = z + 5;
        bool ha = za < D;
        // fresh add-load only; subtract comes from the save-list
        float4 Az = ha ? *(const float4*)(Ib + (size_t)za * SLICE) : Z4;
        float4 Bz = ha ? *(const float4*)(Jb + (size_t)za * SLICE) : Z4;

        // stage own 4 z-sums per field (f32)
#pragma unroll
        for (int f = 0; f < 5; ++f)
            *(float4*)&lds[r][f][4 + x0] = make_float4(s[f][0], s[f][1], s[f][2], s[f][3]);
        __syncthreads();

        // x-window: neighborhood [x0-4, x0+7] = L(4) + own(4) + R(4)
        unsigned char* op = ob + (size_t)z * (H * FROW);
#pragma unroll
        for (int f = 0; f < 5; ++f) {
            float4 Lv = *(const float4*)&lds[r][f][x0];        // x0-4..x0-1
            float4 Rv = *(const float4*)&lds[r][f][x0 + 8];    // x0+4..x0+7
            float p0 = Lv.x;
            float p1 = p0 + Lv.y;
            float p2 = p1 + Lv.z;
            float p3 = p2 + Lv.w;
            float p4 = p3 + s[f][0];
            float p5 = p4 + s[f][1];
            float p6 = p5 + s[f][2];
            float p7 = p6 + s[f][3];
            float p8 = p7 + Rv.x;
            float p9 = p8 + Rv.y;
            float p10 = p9 + Rv.z;
            float p11 = p10 + Rv.w;
            *(unsigned int*)(op + f * W) = pk4(p8, p9 - p0, p10 - p1, p11 - p2);
        }
        __syncthreads();   // protect LDS before next dz overwrite

        // slide the z-window: add fresh, subtract saved (register reuse)
        float4 As = savI[dz], Bs = savJ[dz];
        float ae[4] = {Az.x, Az.y, Az.z, Az.w};
        float be[4] = {Bz.x, Bz.y, Bz.z, Bz.w};
        float al[4] = {As.x, As.y, As.z, As.w};
        float bl[4] = {Bs.x, Bs.y, Bs.z, Bs.w};
#pragma unroll
        for (int i = 0; i < 4; ++i) {
            s[0][i] += ae[i] - al[i];
            s[1][i] += be[i] - bl[i];
            s[2][i] += ae[i] * ae[i] - al[i] * al[i];
            s[3][i] += be[i] * be[i] - bl[i] * bl[i];
            s[4][i] += ae[i] * be[i] - al[i] * bl[i];
        }
    }
}

// ---- pass 2: thin y-slide + cc + reduce (proven) -------------------------
__global__ __launch_bounds__(TPB_Y) void pass_y(const unsigned char* __restrict__ A,
                                                double* __restrict__ partials) {
    int tid = threadIdx.x;
    int t = blockIdx.x * TPB_Y + tid;
    int xg = t % XGY;
    int tup = t / XGY;
    int yc = tup % NCHY;
    int z  = (tup / NCHY) % D;
    int b  = tup / (NCHY * D);
    int x0 = xg * 8;
    const unsigned char* __restrict__ base =
        A + (size_t)(b * D + z) * H * FROW + x0;
    int y0 = yc * CHY;

    float s[5][8];
#pragma unroll
    for (int f = 0; f < 5; ++f)
#pragma unroll
        for (int i = 0; i < 8; ++i) s[f][i] = 0.f;

    int ylo = y0 - 4 < 0 ? 0 : y0 - 4;
    int yhi = y0 + 4 > H - 1 ? H - 1 : y0 + 4;
    for (int yy = ylo; yy <= yhi; ++yy) {
        const unsigned char* rp = base + (size_t)yy * FROW;
#pragma unroll
        for (int f = 0; f < 5; ++f) {
            uint2 v = *(const uint2*)(rp + f * W);
            float u[8]; up8(v, u);
#pragma unroll
            for (int i = 0; i < 8; ++i) s[f][i] += u[i];
        }
    }

    double acc = 0.0;
#pragma unroll
    for (int dy = 0; dy < CHY; ++dy) {
        int ye = y0 + dy + 5, yl = y0 + dy - 4;
        bool he = ye < H, hl = yl >= 0;
        uint2 pe[5], pl[5];
        const unsigned char* pre = base + (size_t)(he ? ye : 0) * FROW;
        const unsigned char* prl = base + (size_t)(hl ? yl : 0) * FROW;
#pragma unroll
        for (int f = 0; f < 5; ++f) {
            pe[f] = he ? *(const uint2*)(pre + f * W) : make_uint2(0u, 0u);
            pl[f] = hl ? *(const uint2*)(prl + f * W) : make_uint2(0u, 0u);
        }

        float rowcc = 0.f;
#pragma unroll
        for (int i = 0; i < 8; ++i) {
            float Is = s[0][i], Js = s[1][i];
            float I2s = s[2][i], J2s = s[3][i], IJs = s[4][i];
            float tI = RW * Is;
            float cross = __builtin_fmaf(-tI, Js, IJs);
            float Iv    = __builtin_fmaf(-tI, Is, I2s);
            float Jv    = __builtin_fmaf(-(RW * Js), Js, J2s);
            float den   = __builtin_fmaf(Iv, Jv, 1e-5f);
            rowcc = __builtin_fmaf(cross * cross, __builtin_amdgcn_rcpf(den), rowcc);
        }
        acc += (double)rowcc;

#pragma unroll
        for (int f = 0; f < 5; ++f) {
            float ue[8], ul[8];
            up8(pe[f], ue); up8(pl[f], ul);
#pragma unroll
            for (int i = 0; i < 8; ++i) s[f][i] += ue[i] - ul[i];
        }
    }

    // deterministic block reduction
#pragma unroll
    for (int off = 32; off > 0; off >>= 1) acc += __shfl_down(acc, off);
    __shared__ double sm[TPB_Y / 64];
    if ((tid & 63) == 0) sm[tid >> 6] = acc;
    __syncthreads();
    if (tid == 0) {
        double tt = 0.0;
#pragma unroll
        for (int i = 0; i < TPB_Y / 64; ++i) tt += sm[i];
        partials[blockIdx.x] = tt;
    }
}

// ---- final deterministic reduce ------------------------------------------
__global__ __launch_bounds__(256) void finalize(const double* __restrict__ p,
                                                float* __restrict__ out) {
    double v = 0.0;
    for (int i = threadIdx.x; i < NBLK_Y; i += 256) v += p[i];
#pragma unroll
    for (int off = 32; off > 0; off >>= 1) v += __shfl_down(v, off);
    __shared__ double sm[4];
    int lane = threadIdx.x & 63, wid = threadIdx.x >> 6;
    if (lane == 0) sm[wid] = v;
    __syncthreads();
    if (threadIdx.x == 0) {
        double tt = 0.0;
#pragma unroll
        for (int i = 0; i < 4; ++i) tt += sm[i];
        out[0] = (float)(1.0 - tt / (double)((double)BATCH * (double)NVOX));
    }
}

extern "C" void kernel_launch(void* const* d_in, const int* in_sizes, int n_in,
                              void* d_out, int out_size, void* d_ws, size_t ws_size,
                              hipStream_t stream) {
    const float* I = (const float*)d_in[0];
    const float* J = (const float*)d_in[1];
    float* out = (float*)d_out;

    // ws: bufA (41 MB fp8) | partials (NBLK_Y f64)
    size_t bufsz = ((size_t)BATCH * 5 * NVOX + 255) / 256 * 256;
    unsigned char* bufA = (unsigned char*)d_ws;
    double* partials = (double*)(bufA + bufsz);

    pass_zx<<<NBLK_ZX, TPB_ZX, 0, stream>>>(I, J, bufA);
    pass_y<<<NBLK_Y, TPB_Y, 0, stream>>>(bufA, partials);
    finalize<<<1, 256, 0, stream>>>(partials, out);
}

// Round 14
// 64.078 us; speedup vs baseline: 1.0678x; 1.0678x over previous
//
#include <hip/hip_runtime.h>

// NCC loss (B=2, C=1, 160^3 f32, 9^3 box window). Two passes + reduce.
// pass_pzx: block = (b, y, x-tile 80, z-chunk 32). 400 threads; staging phase
//           = exactly ONE (slice, 8x) unit per thread: x-windowed products
//           computed in registers (prefix over 16) -> bf16 LDS [5][40][80].
//           One barrier. Compute phase (320 threads): 9-tap z-window over
//           LDS -> fp8 bufA [b][z][y][f][x], 2 z-outputs per thread.
// pass_y  : thin y-slide (8-wide, CHY=2) over xz-windowed fp8 rows + cc +
//           deterministic reduction (proven, R10).
// finalize: deterministic reduce.

typedef float floatx2 __attribute__((ext_vector_type(2)));

constexpr int W = 160, H = 160, D = 160;
constexpr int SLICE = W * H;
constexpr int NVOX  = W * H * D;
constexpr int BATCH = 2;
constexpr int FROW  = 5 * W;             // 800 B per (b,z,y) row-group
constexpr float RW  = 1.0f / 729.0f;

// pass_pzx geometry
constexpr int TPB_P = 400;               // 400 staging units -> 1 per thread
constexpr int XT    = 80;                // x-tile width
constexpr int NXT   = W / XT;            // 2
constexpr int CZ    = 32;                // z outputs per block
constexpr int NCZ   = D / CZ;            // 5
constexpr int ZS    = CZ + 8;            // 40 staged slices
constexpr int NBLK_P = BATCH * H * NXT * NCZ;    // 3200

// pass_y geometry (proven)
constexpr int TPB_Y = 256;
constexpr int XGY   = W / 8;             // 20
constexpr int CHY   = 2, NCHY = H / CHY; // 80
constexpr int NTH_Y = BATCH * D * NCHY * XGY;    // 512,000
constexpr int NBLK_Y = NTH_Y / TPB_Y;            // 2000

// ---- fp8 / bf16 helpers --------------------------------------------------
__device__ inline unsigned int pk4(float a, float b, float c, float d) {
    unsigned int u = 0;
    u = __builtin_amdgcn_cvt_pk_fp8_f32(a, b, u, false);
    u = __builtin_amdgcn_cvt_pk_fp8_f32(c, d, u, true);
    return u;
}
__device__ inline void up8(uint2 v, float* o) {
    floatx2 t;
    t = __builtin_amdgcn_cvt_pk_f32_fp8(v.x, false); o[0] = t[0]; o[1] = t[1];
    t = __builtin_amdgcn_cvt_pk_f32_fp8(v.x, true);  o[2] = t[0]; o[3] = t[1];
    t = __builtin_amdgcn_cvt_pk_f32_fp8(v.y, false); o[4] = t[0]; o[5] = t[1];
    t = __builtin_amdgcn_cvt_pk_f32_fp8(v.y, true);  o[6] = t[0]; o[7] = t[1];
}
__device__ inline unsigned short f2bf(float f) {
    unsigned int u = __builtin_bit_cast(unsigned int, f);
    u += 0x7fffu + ((u >> 16) & 1u);
    return (unsigned short)(u >> 16);
}
__device__ inline unsigned int bfpack2(float lo, float hi) {
    return (unsigned int)f2bf(lo) | ((unsigned int)f2bf(hi) << 16);
}
__device__ inline float bflo(unsigned int u) {
    return __builtin_bit_cast(float, u << 16);
}
__device__ inline float bfhi(unsigned int u) {
    return __builtin_bit_cast(float, u & 0xffff0000u);
}

// ---- pass 1: x-window at staging (regs) + z-window from LDS --------------
__global__ __launch_bounds__(TPB_P) void pass_pzx(const float* __restrict__ I,
                                                  const float* __restrict__ J,
                                                  unsigned char* __restrict__ outA) {
    __shared__ unsigned short xw[5][ZS][XT];   // bf16, 32000 B

    int blk = blockIdx.x;
    int zc = blk % NCZ;
    int xt = (blk / NCZ) % NXT;
    int y  = (blk / (NCZ * NXT)) % H;
    int b  = blk / (NCZ * NXT * H);
    int tx0 = xt * XT;
    int zbase = zc * CZ - 4;
    const float* Ib = I + (size_t)b * NVOX + y * W;
    const float* Jb = J + (size_t)b * NVOX + y * W;

    // ---- staging: exactly one (slice zs, 8-x) unit per thread ------------
    const float4 Z4 = make_float4(0.f, 0.f, 0.f, 0.f);
    {
        int u = threadIdx.x;             // 0..399 == ZS*10 units
        int zs = u / 10;
        int xu = u % 10;
        int gxs = tx0 + xu * 8;          // first output x of this unit
        int gz = zbase + zs;
        float a[16], c[16];
        if (gz >= 0 && gz < D) {
            const float* ip = Ib + (size_t)gz * SLICE + gxs;
            const float* jp = Jb + (size_t)gz * SLICE + gxs;
            float4 A0 = (gxs >= 4)      ? *(const float4*)(ip - 4) : Z4;
            float4 A1 = *(const float4*)(ip);
            float4 A2 = *(const float4*)(ip + 4);
            float4 A3 = (gxs + 11 < W)  ? *(const float4*)(ip + 8) : Z4;
            float4 C0 = (gxs >= 4)      ? *(const float4*)(jp - 4) : Z4;
            float4 C1 = *(const float4*)(jp);
            float4 C2 = *(const float4*)(jp + 4);
            float4 C3 = (gxs + 11 < W)  ? *(const float4*)(jp + 8) : Z4;
            float at[16] = {A0.x,A0.y,A0.z,A0.w, A1.x,A1.y,A1.z,A1.w,
                            A2.x,A2.y,A2.z,A2.w, A3.x,A3.y,A3.z,A3.w};
            float ct[16] = {C0.x,C0.y,C0.z,C0.w, C1.x,C1.y,C1.z,C1.w,
                            C2.x,C2.y,C2.z,C2.w, C3.x,C3.y,C3.z,C3.w};
#pragma unroll
            for (int k = 0; k < 16; ++k) { a[k] = at[k]; c[k] = ct[k]; }
        } else {
#pragma unroll
            for (int k = 0; k < 16; ++k) { a[k] = 0.f; c[k] = 0.f; }
        }
        // per field: prefix over 16, window sums for 8 outputs, bf16 store
#pragma unroll
        for (int f = 0; f < 5; ++f) {
            float v[16];
#pragma unroll
            for (int k = 0; k < 16; ++k) {
                float x = a[k], yv = c[k];
                v[k] = (f == 0) ? x : (f == 1) ? yv :
                       (f == 2) ? x * x : (f == 3) ? yv * yv : x * yv;
            }
            float P[16];
            P[0] = v[0];
#pragma unroll
            for (int k = 1; k < 16; ++k) P[k] = P[k - 1] + v[k];
            float w[8];
            w[0] = P[8];
#pragma unroll
            for (int j = 1; j < 8; ++j) w[j] = P[j + 8] - P[j - 1];
            uint2 pk;
            pk.x = bfpack2(w[0], w[1]);
            pk.y = bfpack2(w[2], w[3]);
            uint2 pk2;
            pk2.x = bfpack2(w[4], w[5]);
            pk2.y = bfpack2(w[6], w[7]);
            *(uint2*)&xw[f][zs][xu * 8]     = pk;
            *(uint2*)&xw[f][zs][xu * 8 + 4] = pk2;
        }
    }

    __syncthreads();

    // ---- compute: 9-tap z-window over LDS, emit fp8 (320 threads) --------
    if (threadIdx.x < 320) {
        int xg = threadIdx.x % 20;       // 4-x group (tile-local)
        int zl = threadIdx.x / 20;       // 0..15, owns 2 z outputs
        int x0l = xg * 4;
        int zo0 = zl * 2;

        float acc[5][4];
#pragma unroll
        for (int f = 0; f < 5; ++f)
#pragma unroll
            for (int i = 0; i < 4; ++i) acc[f][i] = 0.f;

#pragma unroll
        for (int k = 0; k < 9; ++k) {
#pragma unroll
            for (int f = 0; f < 5; ++f) {
                uint2 v = *(const uint2*)&xw[f][zo0 + k][x0l];
                acc[f][0] += bflo(v.x); acc[f][1] += bfhi(v.x);
                acc[f][2] += bflo(v.y); acc[f][3] += bfhi(v.y);
            }
        }

        int gz0 = zc * CZ + zo0;
        unsigned char* op0 = outA + ((size_t)(b * D + gz0) * H + y) * FROW + tx0 + x0l;
#pragma unroll
        for (int f = 0; f < 5; ++f)
            *(unsigned int*)(op0 + f * W) = pk4(acc[f][0], acc[f][1], acc[f][2], acc[f][3]);

        // slide one step
#pragma unroll
        for (int f = 0; f < 5; ++f) {
            uint2 ve = *(const uint2*)&xw[f][zo0 + 9][x0l];
            uint2 vl = *(const uint2*)&xw[f][zo0][x0l];
            acc[f][0] += bflo(ve.x) - bflo(vl.x);
            acc[f][1] += bfhi(ve.x) - bfhi(vl.x);
            acc[f][2] += bflo(ve.y) - bflo(vl.y);
            acc[f][3] += bfhi(ve.y) - bfhi(vl.y);
        }
        unsigned char* op1 = op0 + (size_t)H * FROW;
#pragma unroll
        for (int f = 0; f < 5; ++f)
            *(unsigned int*)(op1 + f * W) = pk4(acc[f][0], acc[f][1], acc[f][2], acc[f][3]);
    }
}

// ---- pass 2: thin y-slide + cc + reduce (proven) -------------------------
__global__ __launch_bounds__(TPB_Y) void pass_y(const unsigned char* __restrict__ A,
                                                double* __restrict__ partials) {
    int tid = threadIdx.x;
    int t = blockIdx.x * TPB_Y + tid;
    int xg = t % XGY;
    int tup = t / XGY;
    int yc = tup % NCHY;
    int z  = (tup / NCHY) % D;
    int b  = tup / (NCHY * D);
    int x0 = xg * 8;
    const unsigned char* __restrict__ base =
        A + (size_t)(b * D + z) * H * FROW + x0;
    int y0 = yc * CHY;

    float s[5][8];
#pragma unroll
    for (int f = 0; f < 5; ++f)
#pragma unroll
        for (int i = 0; i < 8; ++i) s[f][i] = 0.f;

    int ylo = y0 - 4 < 0 ? 0 : y0 - 4;
    int yhi = y0 + 4 > H - 1 ? H - 1 : y0 + 4;
    for (int yy = ylo; yy <= yhi; ++yy) {
        const unsigned char* rp = base + (size_t)yy * FROW;
#pragma unroll
        for (int f = 0; f < 5; ++f) {
            uint2 v = *(const uint2*)(rp + f * W);
            float u[8]; up8(v, u);
#pragma unroll
            for (int i = 0; i < 8; ++i) s[f][i] += u[i];
        }
    }

    double acc = 0.0;
#pragma unroll
    for (int dy = 0; dy < CHY; ++dy) {
        int ye = y0 + dy + 5, yl = y0 + dy - 4;
        bool he = ye < H, hl = yl >= 0;
        uint2 pe[5], pl[5];
        const unsigned char* pre = base + (size_t)(he ? ye : 0) * FROW;
        const unsigned char* prl = base + (size_t)(hl ? yl : 0) * FROW;
#pragma unroll
        for (int f = 0; f < 5; ++f) {
            pe[f] = he ? *(const uint2*)(pre + f * W) : make_uint2(0u, 0u);
            pl[f] = hl ? *(const uint2*)(prl + f * W) : make_uint2(0u, 0u);
        }

        float rowcc = 0.f;
#pragma unroll
        for (int i = 0; i < 8; ++i) {
            float Is = s[0][i], Js = s[1][i];
            float I2s = s[2][i], J2s = s[3][i], IJs = s[4][i];
            float tI = RW * Is;
            float cross = __builtin_fmaf(-tI, Js, IJs);
            float Iv    = __builtin_fmaf(-tI, Is, I2s);
            float Jv    = __builtin_fmaf(-(RW * Js), Js, J2s);
            float den   = __builtin_fmaf(Iv, Jv, 1e-5f);
            rowcc = __builtin_fmaf(cross * cross, __builtin_amdgcn_rcpf(den), rowcc);
        }
        acc += (double)rowcc;

#pragma unroll
        for (int f = 0; f < 5; ++f) {
            float ue[8], ul[8];
            up8(pe[f], ue); up8(pl[f], ul);
#pragma unroll
            for (int i = 0; i < 8; ++i) s[f][i] += ue[i] - ul[i];
        }
    }

    // deterministic block reduction
#pragma unroll
    for (int off = 32; off > 0; off >>= 1) acc += __shfl_down(acc, off);
    __shared__ double sm[TPB_Y / 64];
    if ((tid & 63) == 0) sm[tid >> 6] = acc;
    __syncthreads();
    if (tid == 0) {
        double tt = 0.0;
#pragma unroll
        for (int i = 0; i < TPB_Y / 64; ++i) tt += sm[i];
        partials[blockIdx.x] = tt;
    }
}

// ---- final deterministic reduce ------------------------------------------
__global__ __launch_bounds__(256) void finalize(const double* __restrict__ p,
                                                float* __restrict__ out) {
    double v = 0.0;
    for (int i = threadIdx.x; i < NBLK_Y; i += 256) v += p[i];
#pragma unroll
    for (int off = 32; off > 0; off >>= 1) v += __shfl_down(v, off);
    __shared__ double sm[4];
    int lane = threadIdx.x & 63, wid = threadIdx.x >> 6;
    if (lane == 0) sm[wid] = v;
    __syncthreads();
    if (threadIdx.x == 0) {
        double tt = 0.0;
#pragma unroll
        for (int i = 0; i < 4; ++i) tt += sm[i];
        out[0] = (float)(1.0 - tt / (double)((double)BATCH * (double)NVOX));
    }
}

extern "C" void kernel_launch(void* const* d_in, const int* in_sizes, int n_in,
                              void* d_out, int out_size, void* d_ws, size_t ws_size,
                              hipStream_t stream) {
    const float* I = (const float*)d_in[0];
    const float* J = (const float*)d_in[1];
    float* out = (float*)d_out;

    // ws: bufA (41 MB fp8) | partials (NBLK_Y f64)
    size_t bufsz = ((size_t)BATCH * 5 * NVOX + 255) / 256 * 256;
    unsigned char* bufA = (unsigned char*)d_ws;
    double* partials = (double*)(bufA + bufsz);

    pass_pzx<<<NBLK_P, TPB_P, 0, stream>>>(I, J, bufA);
    pass_y<<<NBLK_Y, TPB_Y, 0, stream>>>(bufA, partials);
    finalize<<<1, 256, 0, stream>>>(partials, out);
}